// Round 5
// baseline (394.914 us; speedup 1.0000x reference)
//
#include <hip/hip_runtime.h>
#include <hip/hip_fp16.h>
#include <math.h>
#include <stddef.h>

#define D_DIM 128
#define NUM_RBF 20
typedef unsigned short ushort_t;
constexpr float PI_F = 3.14159265358979323846f;
constexpr float CUT_OFF_F = 5.0f;
constexpr float SILU_SCALE_F = 1.0f / 0.6f;

__device__ __forceinline__ unsigned int pack2h(float a, float b) {
  __half2 h2 = __floats2half2_rn(a, b);
  return *reinterpret_cast<unsigned int*>(&h2);
}
__device__ __forceinline__ float h2f(ushort_t u) {
  __half h = __ushort_as_half(u);
  return __half2float(h);
}

// ---------------------------------------------------------------------------
// Fused node projection: s = scaled_silu(X @ W1 + b1) @ W2 + b2
// Output: fp16 PLANE layout [N][3][128]: s_half[n*384 + comp*128 + chan]
//         = s[n][3*chan + comp].
// Achieved by staging W2 into LDS with columns permuted (q -> (q%3)*128+q/3)
// and permuting the b2 init, so acc2[i][m][j] IS plane element (m, c0+j).
// (R4 bug: stored natural order but node read plane order.)
// ---------------------------------------------------------------------------
__global__ __launch_bounds__(256) void proj_kernel(
    const float* __restrict__ X, const float* __restrict__ W1,
    const float* __restrict__ b1, const float* __restrict__ W2,
    const float* __restrict__ b2, ushort_t* __restrict__ s_half, int N) {
  __shared__ float smA[32 * 128];    // xs then hs
  __shared__ float smB[128 * 128];   // W1 then W2 chunk
  float* xs = smA;
  float* hs = smA;
  float* w1s = smB;
  float* w2c = smB;

  const int t = threadIdx.x;
  const int nb = blockIdx.x * 32;

  {
    const float4* Xv = reinterpret_cast<const float4*>(X);
    float4* xsv = reinterpret_cast<float4*>(xs);
#pragma unroll
    for (int i = 0; i < 4; ++i) {
      int f4 = t + i * 256;
      int node = nb + (f4 >> 5);
      xsv[f4] = (node < N) ? Xv[(size_t)nb * 32 + f4]
                           : make_float4(0.f, 0.f, 0.f, 0.f);
    }
  }
  {
    const float4* W1v = reinterpret_cast<const float4*>(W1);
    float4* wv = reinterpret_cast<float4*>(w1s);
#pragma unroll
    for (int i = 0; i < 16; ++i) wv[t + i * 256] = W1v[t + i * 256];
  }
  __syncthreads();

  const int c0 = (t & 31) * 4;
  const int r0 = (t >> 5) * 4;

  float acc1[4][4] = {};
  for (int k = 0; k < 128; k += 4) {
    float xa[4][4];
#pragma unroll
    for (int i = 0; i < 4; ++i) {
      float4 xt = *reinterpret_cast<const float4*>(&xs[(r0 + i) * 128 + k]);
      xa[i][0] = xt.x; xa[i][1] = xt.y; xa[i][2] = xt.z; xa[i][3] = xt.w;
    }
#pragma unroll
    for (int kk = 0; kk < 4; ++kk) {
      float4 wv = *reinterpret_cast<const float4*>(&w1s[(k + kk) * 128 + c0]);
      float wa[4] = {wv.x, wv.y, wv.z, wv.w};
#pragma unroll
      for (int i = 0; i < 4; ++i)
#pragma unroll
        for (int j = 0; j < 4; ++j) acc1[i][j] += xa[i][kk] * wa[j];
    }
  }
  __syncthreads();

  {
    float b1v[4];
#pragma unroll
    for (int j = 0; j < 4; ++j) b1v[j] = b1[c0 + j];
#pragma unroll
    for (int i = 0; i < 4; ++i) {
#pragma unroll
      for (int j = 0; j < 4; ++j) {
        float h = acc1[i][j] + b1v[j];
        h = h * SILU_SCALE_F / (1.0f + expf(-h));
        hs[(r0 + i) * 128 + c0 + j] = h;
      }
    }
  }

  // acc2[i][m][j] = plane element (comp=m, chan=c0+j) = s column 3*(c0+j)+m
  float acc2[4][3][4];
#pragma unroll
  for (int m = 0; m < 3; ++m)
#pragma unroll
    for (int j = 0; j < 4; ++j) {
      float bv = b2[3 * (c0 + j) + m];
#pragma unroll
      for (int i = 0; i < 4; ++i) acc2[i][m][j] = bv;
    }

  for (int kc = 0; kc < 128; kc += 32) {
    __syncthreads();
    {
      // stage W2 rows kc..kc+31 with PERMUTED columns:
      // lds[kk*384 + (q%3)*128 + q/3] = W2[kc+kk][q]
      const float4* W2v = reinterpret_cast<const float4*>(W2);
#pragma unroll
      for (int i = 0; i < 12; ++i) {
        int g = t + i * 256;              // 0..3071 (32 rows * 96 float4)
        float4 v = W2v[(size_t)kc * 96 + g];
        int kk = g / 96;
        int qb = (g % 96) * 4;
        float vals[4] = {v.x, v.y, v.z, v.w};
#pragma unroll
        for (int j = 0; j < 4; ++j) {
          int q = qb + j;
          w2c[kk * 384 + (q % 3) * 128 + q / 3] = vals[j];
        }
      }
    }
    __syncthreads();
    for (int kk = 0; kk < 32; ++kk) {
      float xr[4];
#pragma unroll
      for (int i = 0; i < 4; ++i) xr[i] = hs[(r0 + i) * 128 + kc + kk];
#pragma unroll
      for (int m = 0; m < 3; ++m) {
        float4 wv = *reinterpret_cast<const float4*>(&w2c[kk * 384 + m * 128 + c0]);
        float wa[4] = {wv.x, wv.y, wv.z, wv.w};
#pragma unroll
        for (int i = 0; i < 4; ++i)
#pragma unroll
          for (int j = 0; j < 4; ++j) acc2[i][m][j] += xr[i] * wa[j];
      }
    }
  }

  // ---- store s as fp16 planes [N][3][128] (coalesced uint2) ----
#pragma unroll
  for (int i = 0; i < 4; ++i) {
    int node = nb + r0 + i;
    if (node < N) {
      ushort_t* row = s_half + (size_t)node * 384;
#pragma unroll
      for (int m = 0; m < 3; ++m) {
        uint2 v = make_uint2(pack2h(acc2[i][m][0], acc2[i][m][1]),
                             pack2h(acc2[i][m][2], acc2[i][m][3]));
        *reinterpret_cast<uint2*>(row + m * 128 + c0) = v;
      }
    }
  }
}

// ---------------------------------------------------------------------------
// vf fp32 [N][128][3] -> fp16 plane layout [N][3][128]
// ---------------------------------------------------------------------------
__global__ void vf_cast_kernel(const float* __restrict__ vf,
                               ushort_t* __restrict__ vf_half, int total) {
  int i = blockIdx.x * 256 + threadIdx.x;  // over N*128
  if (i >= total) return;
  const int n = i >> 7, d = i & 127;
  const float* p = vf + (size_t)n * 384 + 3 * d;
  ushort_t* row = vf_half + (size_t)n * 384;
  row[d]       = __half_as_ushort(__float2half_rn(p[0]));
  row[128 + d] = __half_as_ushort(__float2half_rn(p[1]));
  row[256 + d] = __half_as_ushort(__float2half_rn(p[2]));
}

// ---------------------------------------------------------------------------
// CSR build
// ---------------------------------------------------------------------------
__global__ void zero_kernel(int* __restrict__ p, int n) {
  int i = blockIdx.x * 256 + threadIdx.x;
  if (i < n) p[i] = 0;
}

__global__ void hist_kernel(const int* __restrict__ tgt, int* __restrict__ counts,
                            int E) {
  int e = blockIdx.x * 256 + threadIdx.x;
  if (e < E) atomicAdd(&counts[tgt[e]], 1);
}

__global__ void chunk_sum_kernel(const int* __restrict__ counts,
                                 int* __restrict__ chunk_sums, int N) {
  __shared__ int red[256];
  int b = blockIdx.x, t = threadIdx.x;
  int base = b * 1024 + t * 4;
  int s = 0;
#pragma unroll
  for (int j = 0; j < 4; ++j) s += (base + j < N) ? counts[base + j] : 0;
  red[t] = s;
  __syncthreads();
  for (int off = 128; off > 0; off >>= 1) {
    if (t < off) red[t] += red[t + off];
    __syncthreads();
  }
  if (t == 0) chunk_sums[b] = red[0];
}

__global__ void scan_chunks_kernel(int* __restrict__ chunk_sums,
                                   int* __restrict__ offsets, int nch, int N,
                                   int E) {
  int t = threadIdx.x;  // one wave; nch <= 64
  int v = (t < nch) ? chunk_sums[t] : 0;
  int orig = v;
#pragma unroll
  for (int off = 1; off < 64; off <<= 1) {
    int y = __shfl_up(v, off);
    if (t >= off) v += y;
  }
  if (t < nch) chunk_sums[t] = v - orig;
  if (t == 0) offsets[N] = E;
}

__global__ void scan_block_kernel(const int* __restrict__ counts,
                                  const int* __restrict__ chunk_off,
                                  int* __restrict__ offsets,
                                  int* __restrict__ cursor, int N) {
  __shared__ int part[256];
  int b = blockIdx.x, t = threadIdx.x;
  int base = b * 1024 + t * 4;
  int v[4];
#pragma unroll
  for (int j = 0; j < 4; ++j) v[j] = (base + j < N) ? counts[base + j] : 0;
  int local = v[0] + v[1] + v[2] + v[3];
  part[t] = local;
  __syncthreads();
  for (int off = 1; off < 256; off <<= 1) {
    int x = 0;
    if (t >= off) x = part[t - off];
    __syncthreads();
    if (t >= off) part[t] += x;
    __syncthreads();
  }
  int run = chunk_off[b] + (part[t] - local);
#pragma unroll
  for (int j = 0; j < 4; ++j) {
    if (base + j < N) {
      offsets[base + j] = run;
      cursor[base + j] = run;
      run += v[j];
    }
  }
}

// ---------------------------------------------------------------------------
// Fused edge geometry + CSR scatter (dir, rbf, src into CSR-sorted slots).
// ---------------------------------------------------------------------------
__global__ void edge_geom_kernel(const float* __restrict__ pos,
                                 const int* __restrict__ src,
                                 const int* __restrict__ tgt,
                                 int* __restrict__ cursor,
                                 float4* __restrict__ dir4_s,
                                 float4* __restrict__ rb4_s,
                                 int* __restrict__ src_s, int E) {
  int e = blockIdx.x * 256 + threadIdx.x;
  if (e >= E) return;
  const int sn = src[e];
  const int tn = tgt[e];
  const float rx = pos[tn * 3 + 0] - pos[sn * 3 + 0];
  const float ry = pos[tn * 3 + 1] - pos[sn * 3 + 1];
  const float rz = pos[tn * 3 + 2] - pos[sn * 3 + 2];
  const float dist = sqrtf(rx * rx + ry * ry + rz * rz);
  const float inv = 1.0f / dist;

  const float ang = dist * (PI_F / CUT_OFF_F);
  float s1, c1;
  sincosf(ang, &s1, &c1);
  float sk = s1, ck = c1;
  float rb[NUM_RBF];
  rb[0] = s1 * inv;
#pragma unroll
  for (int r = 1; r < NUM_RBF; ++r) {
    float sn2 = sk * c1 + ck * s1;
    ck = ck * c1 - sk * s1;
    sk = sn2;
    rb[r] = sk * inv;
  }

  const int p = atomicAdd(&cursor[tn], 1);
  dir4_s[p] = make_float4(rx * inv, ry * inv, rz * inv, dist);
  src_s[p] = sn;
  float4* o = rb4_s + (size_t)p * 5;
#pragma unroll
  for (int q = 0; q < 5; ++q)
    o[q] = make_float4(rb[4 * q], rb[4 * q + 1], rb[4 * q + 2], rb[4 * q + 3]);
}

// ---------------------------------------------------------------------------
// Node gather. fp16 plane-layout gathers of s and vf (6 ushorts/edge/lane),
// shfl-broadcast src, linear dir/rbf streams, x2 ILP unroll.
// ---------------------------------------------------------------------------
#define NODES_PER_BLOCK 8

__device__ __forceinline__ float cutoff_f(float x) {
  return (x < CUT_OFF_F) ? 0.5f * (1.0f + __cosf(x * (PI_F / CUT_OFF_F))) : 0.f;
}

struct EdgeData {
  float4 dir;
  float4 rb[5];
  float sx, sy, sz, vx, vy, vz;
};

__device__ __forceinline__ void load_edge(int idx, int sn, int d,
                                          const ushort_t* __restrict__ s_half,
                                          const ushort_t* __restrict__ vf_half,
                                          const float4* __restrict__ dir4_s,
                                          const float4* __restrict__ rb4_s,
                                          EdgeData& ed) {
  ed.dir = dir4_s[idx];
#pragma unroll
  for (int q = 0; q < 5; ++q) ed.rb[q] = rb4_s[(size_t)idx * 5 + q];
  const ushort_t* sr = s_half + (size_t)sn * 384;
  ed.sx = h2f(sr[d]); ed.sy = h2f(sr[128 + d]); ed.sz = h2f(sr[256 + d]);
  const ushort_t* vr = vf_half + (size_t)sn * 384;
  ed.vx = h2f(vr[d]); ed.vy = h2f(vr[128 + d]); ed.vz = h2f(vr[256 + d]);
}

__global__ __launch_bounds__(128) void node_kernel(
    const ushort_t* __restrict__ s_half, const ushort_t* __restrict__ vf_half,
    const float4* __restrict__ dir4_s, const float4* __restrict__ rb4_s,
    const int* __restrict__ src_s, const int* __restrict__ offsets,
    const float* __restrict__ Wr, const float* __restrict__ br,
    float* __restrict__ out, int N, int E) {
  const int d = threadIdx.x;
  const int lane = d & 63;

  float wr0[NUM_RBF], wr1[NUM_RBF], wr2[NUM_RBF];
#pragma unroll
  for (int r = 0; r < NUM_RBF; ++r) {
    wr0[r] = Wr[r * 384 + 3 * d + 0];
    wr1[r] = Wr[r * 384 + 3 * d + 1];
    wr2[r] = Wr[r * 384 + 3 * d + 2];
  }
  const float br0 = br[3 * d + 0];
  const float br1 = br[3 * d + 1];
  const float br2 = br[3 * d + 2];

  for (int nn = 0; nn < NODES_PER_BLOCK; ++nn) {
    const int n = blockIdx.x * NODES_PER_BLOCK + nn;
    if (n >= N) break;

    const int start = offsets[n];
    const int end = offsets[n + 1];

    float accs = 0.f, av0 = 0.f, av1 = 0.f, av2 = 0.f;

    for (int base = start; base < end; base += 64) {
      const int m = min(64, end - base);
      int ld = base + lane;
      if (ld >= E) ld = E - 1;
      const int sn_l = src_s[ld];

      int i = 0;
      for (; i + 2 <= m; i += 2) {
        const int sn0 = __shfl(sn_l, i);
        const int sn1 = __shfl(sn_l, i + 1);
        EdgeData e0, e1;
        load_edge(base + i, sn0, d, s_half, vf_half, dir4_s, rb4_s, e0);
        load_edge(base + i + 1, sn1, d, s_half, vf_half, dir4_s, rb4_s, e1);

#pragma unroll
        for (int u = 0; u < 2; ++u) {
          const EdgeData& ed = (u == 0) ? e0 : e1;
          const float* rbf = reinterpret_cast<const float*>(&ed.rb[0]);
          float f0 = br0, f1 = br1, f2 = br2;
#pragma unroll
          for (int r = 0; r < NUM_RBF; ++r) {
            f0 += rbf[r] * wr0[r];
            f1 += rbf[r] * wr1[r];
            f2 += rbf[r] * wr2[r];
          }
          f0 = cutoff_f(f0);
          f1 = cutoff_f(f1);
          f2 = cutoff_f(f2);
          const float m0 = ed.sx * f0;
          const float m1 = ed.sy * f1;
          const float m2 = ed.sz * f2;
          accs += m0;
          av0 += m2 * ed.dir.x + m1 * ed.vx;
          av1 += m2 * ed.dir.y + m1 * ed.vy;
          av2 += m2 * ed.dir.z + m1 * ed.vz;
        }
      }
      if (i < m) {
        const int sn0 = __shfl(sn_l, i);
        EdgeData e0;
        load_edge(base + i, sn0, d, s_half, vf_half, dir4_s, rb4_s, e0);
        const float* rbf = reinterpret_cast<const float*>(&e0.rb[0]);
        float f0 = br0, f1 = br1, f2 = br2;
#pragma unroll
        for (int r = 0; r < NUM_RBF; ++r) {
          f0 += rbf[r] * wr0[r];
          f1 += rbf[r] * wr1[r];
          f2 += rbf[r] * wr2[r];
        }
        f0 = cutoff_f(f0);
        f1 = cutoff_f(f1);
        f2 = cutoff_f(f2);
        const float m0 = e0.sx * f0;
        const float m1 = e0.sy * f1;
        const float m2 = e0.sz * f2;
        accs += m0;
        av0 += m2 * e0.dir.x + m1 * e0.vx;
        av1 += m2 * e0.dir.y + m1 * e0.vy;
        av2 += m2 * e0.dir.z + m1 * e0.vz;
      }
    }

    out[(size_t)n * 384 + 3 * d + 0] = av0;
    out[(size_t)n * 384 + 3 * d + 1] = av1;
    out[(size_t)n * 384 + 3 * d + 2] = av2;
    out[(size_t)N * 384 + (size_t)n * 128 + d] = accs;
  }
}

// ---------------------------------------------------------------------------
extern "C" void kernel_launch(void* const* d_in, const int* in_sizes, int n_in,
                              void* d_out, int out_size, void* d_ws,
                              size_t ws_size, hipStream_t stream) {
  const float* vf  = (const float*)d_in[0];   // [N,128,3]
  const float* X   = (const float*)d_in[1];   // [N,128]
  const float* pos = (const float*)d_in[2];   // [N,3]
  const int* ei    = (const int*)d_in[3];     // [2,E]
  const float* W1  = (const float*)d_in[4];
  const float* b1  = (const float*)d_in[5];
  const float* W2  = (const float*)d_in[6];
  const float* b2  = (const float*)d_in[7];
  const float* Wr  = (const float*)d_in[8];
  const float* br  = (const float*)d_in[9];

  const int N = in_sizes[1] / D_DIM;
  const int E = in_sizes[3] / 2;
  const int* srcI = ei;
  const int* tgtI = ei + E;
  float* out = (float*)d_out;

  // workspace layout (16B-aligned chunks first)
  char* w = (char*)d_ws;
  float4* dir4_s = (float4*)w;   w += (size_t)E * sizeof(float4);
  float4* rb4_s  = (float4*)w;   w += (size_t)E * 5 * sizeof(float4);
  ushort_t* s_half  = (ushort_t*)w; w += (size_t)N * 384 * sizeof(ushort_t);
  ushort_t* vf_half = (ushort_t*)w; w += (size_t)N * 384 * sizeof(ushort_t);
  int* src_s     = (int*)w;      w += (size_t)E * sizeof(int);
  int* counts    = (int*)w;      w += (size_t)N * sizeof(int);
  int* offsets   = (int*)w;      w += (size_t)(N + 1) * sizeof(int);
  int* cursor    = (int*)w;      w += (size_t)N * sizeof(int);
  int* chunks    = (int*)w;      w += 64 * sizeof(int);

  const int nch = (N + 1023) / 1024;  // 49 for N=50000

  zero_kernel<<<(N + 255) / 256, 256, 0, stream>>>(counts, N);
  proj_kernel<<<(N + 31) / 32, 256, 0, stream>>>(X, W1, b1, W2, b2, s_half, N);
  vf_cast_kernel<<<(N * 128 + 255) / 256, 256, 0, stream>>>(vf, vf_half,
                                                            N * 128);
  hist_kernel<<<(E + 255) / 256, 256, 0, stream>>>(tgtI, counts, E);
  chunk_sum_kernel<<<nch, 256, 0, stream>>>(counts, chunks, N);
  scan_chunks_kernel<<<1, 64, 0, stream>>>(chunks, offsets, nch, N, E);
  scan_block_kernel<<<nch, 256, 0, stream>>>(counts, chunks, offsets, cursor, N);
  edge_geom_kernel<<<(E + 255) / 256, 256, 0, stream>>>(pos, srcI, tgtI, cursor,
                                                        dir4_s, rb4_s, src_s, E);
  node_kernel<<<(N + NODES_PER_BLOCK - 1) / NODES_PER_BLOCK, 128, 0, stream>>>(
      s_half, vf_half, dir4_s, rb4_s, src_s, offsets, Wr, br, out, N, E);
}

// Round 6
// 345.077 us; speedup vs baseline: 1.1444x; 1.1444x over previous
//
#include <hip/hip_runtime.h>
#include <hip/hip_fp16.h>
#include <math.h>
#include <stddef.h>

#define D_DIM 128
#define NUM_RBF 20
typedef unsigned short ushort_t;
typedef unsigned int uint_t;
typedef _Float16 h2v __attribute__((ext_vector_type(2)));
constexpr float PI_F = 3.14159265358979323846f;
constexpr float CUT_OFF_F = 5.0f;
constexpr float SILU_SCALE_F = 1.0f / 0.6f;

__device__ __forceinline__ uint_t pack2h(float a, float b) {
  __half2 h2 = __floats2half2_rn(a, b);
  return *reinterpret_cast<uint_t*>(&h2);
}
__device__ __forceinline__ float h2f(ushort_t u) {
  __half h = __ushort_as_half(u);
  return __half2float(h);
}
__device__ __forceinline__ h2v u2h2(uint_t u) {
  h2v r;
  __builtin_memcpy(&r, &u, 4);
  return r;
}

#if defined(__has_builtin)
#if __has_builtin(__builtin_amdgcn_fdot2)
#define HAVE_FDOT2 1
#endif
#endif

__device__ __forceinline__ float fdot2f(h2v a, h2v b, float c) {
#ifdef HAVE_FDOT2
  return __builtin_amdgcn_fdot2(a, b, c, false);
#else
  return c + (float)a.x * (float)b.x + (float)a.y * (float)b.y;
#endif
}

// ---------------------------------------------------------------------------
// Fused node projection: s = scaled_silu(X @ W1 + b1) @ W2 + b2
// Output: fp16, NATURAL order [N][384] (identity column mapping).
// LDS: smA 16KB (xs then hs) + smB 32KB (W1 64-row chunks, W2 16-row chunks)
// = 48KB -> 3 blocks/CU (was 80KB -> 2).
// ---------------------------------------------------------------------------
__global__ __launch_bounds__(256) void proj_kernel(
    const float* __restrict__ X, const float* __restrict__ W1,
    const float* __restrict__ b1, const float* __restrict__ W2,
    const float* __restrict__ b2, ushort_t* __restrict__ s_half, int N) {
  __shared__ float smA[32 * 128];   // xs then hs
  __shared__ float smB[8192];       // W1 chunk (64x128) / W2 chunk (16x384)
  float* xs = smA;
  float* hs = smA;
  float* w1s = smB;
  float* w2c = smB;

  const int t = threadIdx.x;
  const int nb = blockIdx.x * 32;

  {
    const float4* Xv = reinterpret_cast<const float4*>(X);
    float4* xsv = reinterpret_cast<float4*>(xs);
#pragma unroll
    for (int i = 0; i < 4; ++i) {
      int f4 = t + i * 256;
      int node = nb + (f4 >> 5);
      xsv[f4] = (node < N) ? Xv[(size_t)nb * 32 + f4]
                           : make_float4(0.f, 0.f, 0.f, 0.f);
    }
  }
  __syncthreads();

  const int c0 = (t & 31) * 4;
  const int r0 = (t >> 5) * 4;

  // ---- phase 1: h = X @ W1, W1 in 2 chunks of 64 K-rows (32KB) ----
  float acc1[4][4] = {};
  for (int kc1 = 0; kc1 < 128; kc1 += 64) {
    __syncthreads();
    {
      const float4* W1v = reinterpret_cast<const float4*>(W1);
      float4* wv = reinterpret_cast<float4*>(w1s);
#pragma unroll
      for (int i = 0; i < 8; ++i)
        wv[t + i * 256] = W1v[kc1 * 32 + t + i * 256];
    }
    __syncthreads();
    for (int k = 0; k < 64; k += 4) {
      float xa[4][4];
#pragma unroll
      for (int i = 0; i < 4; ++i) {
        float4 xt =
            *reinterpret_cast<const float4*>(&xs[(r0 + i) * 128 + kc1 + k]);
        xa[i][0] = xt.x; xa[i][1] = xt.y; xa[i][2] = xt.z; xa[i][3] = xt.w;
      }
#pragma unroll
      for (int kk = 0; kk < 4; ++kk) {
        float4 wv = *reinterpret_cast<const float4*>(&w1s[(k + kk) * 128 + c0]);
        float wa[4] = {wv.x, wv.y, wv.z, wv.w};
#pragma unroll
        for (int i = 0; i < 4; ++i)
#pragma unroll
          for (int j = 0; j < 4; ++j) acc1[i][j] += xa[i][kk] * wa[j];
      }
    }
  }
  __syncthreads();   // xs reads complete before hs overwrite

  {
    float b1v[4];
#pragma unroll
    for (int j = 0; j < 4; ++j) b1v[j] = b1[c0 + j];
#pragma unroll
    for (int i = 0; i < 4; ++i) {
#pragma unroll
      for (int j = 0; j < 4; ++j) {
        float h = acc1[i][j] + b1v[j];
        h = h * SILU_SCALE_F / (1.0f + expf(-h));
        hs[(r0 + i) * 128 + c0 + j] = h;
      }
    }
  }

  // ---- phase 2: s = h @ W2 + b2, W2 in 8 chunks of 16 K-rows (24KB) ----
  float acc2[4][3][4];
#pragma unroll
  for (int m = 0; m < 3; ++m)
#pragma unroll
    for (int j = 0; j < 4; ++j) {
      float bv = b2[m * 128 + c0 + j];
#pragma unroll
      for (int i = 0; i < 4; ++i) acc2[i][m][j] = bv;
    }

  for (int kc = 0; kc < 128; kc += 16) {
    __syncthreads();
    {
      const float4* W2v = reinterpret_cast<const float4*>(W2);
      float4* wv = reinterpret_cast<float4*>(w2c);
#pragma unroll
      for (int i = 0; i < 6; ++i)
        wv[t + i * 256] = W2v[(size_t)kc * 96 + t + i * 256];
    }
    __syncthreads();
    for (int kk = 0; kk < 16; ++kk) {
      float xr[4];
#pragma unroll
      for (int i = 0; i < 4; ++i) xr[i] = hs[(r0 + i) * 128 + kc + kk];
#pragma unroll
      for (int m = 0; m < 3; ++m) {
        float4 wv = *reinterpret_cast<const float4*>(&w2c[kk * 384 + m * 128 + c0]);
        float wa[4] = {wv.x, wv.y, wv.z, wv.w};
#pragma unroll
        for (int i = 0; i < 4; ++i)
#pragma unroll
          for (int j = 0; j < 4; ++j) acc2[i][m][j] += xr[i] * wa[j];
      }
    }
  }

  // ---- store s as fp16, natural order, coalesced uint2 ----
#pragma unroll
  for (int i = 0; i < 4; ++i) {
    int node = nb + r0 + i;
    if (node < N) {
      ushort_t* row = s_half + (size_t)node * 384;
#pragma unroll
      for (int m = 0; m < 3; ++m) {
        uint2 v = make_uint2(pack2h(acc2[i][m][0], acc2[i][m][1]),
                             pack2h(acc2[i][m][2], acc2[i][m][3]));
        *reinterpret_cast<uint2*>(row + m * 128 + c0) = v;
      }
    }
  }
}

// ---------------------------------------------------------------------------
// vf fp32 -> fp16, pure elementwise (natural layout), fully vectorized.
// One thread = 8 elements. total8 = N*384/8.
// ---------------------------------------------------------------------------
__global__ void vf_cast_kernel(const float* __restrict__ vf,
                               ushort_t* __restrict__ vf_half, int total8) {
  int i = blockIdx.x * 256 + threadIdx.x;
  if (i >= total8) return;
  const float4* v4 = reinterpret_cast<const float4*>(vf);
  float4 a = v4[2 * i], b = v4[2 * i + 1];
  uint4 r = make_uint4(pack2h(a.x, a.y), pack2h(a.z, a.w),
                       pack2h(b.x, b.y), pack2h(b.z, b.w));
  reinterpret_cast<uint4*>(vf_half)[i] = r;
}

// ---------------------------------------------------------------------------
// CSR build
// ---------------------------------------------------------------------------
__global__ void zero_kernel(int* __restrict__ p, int n) {
  int i = blockIdx.x * 256 + threadIdx.x;
  if (i < n) p[i] = 0;
}

__global__ void hist_kernel(const int* __restrict__ tgt, int* __restrict__ counts,
                            int E) {
  int e = blockIdx.x * 256 + threadIdx.x;
  if (e < E) atomicAdd(&counts[tgt[e]], 1);
}

__global__ void chunk_sum_kernel(const int* __restrict__ counts,
                                 int* __restrict__ chunk_sums, int N) {
  __shared__ int red[256];
  int b = blockIdx.x, t = threadIdx.x;
  int base = b * 1024 + t * 4;
  int s = 0;
#pragma unroll
  for (int j = 0; j < 4; ++j) s += (base + j < N) ? counts[base + j] : 0;
  red[t] = s;
  __syncthreads();
  for (int off = 128; off > 0; off >>= 1) {
    if (t < off) red[t] += red[t + off];
    __syncthreads();
  }
  if (t == 0) chunk_sums[b] = red[0];
}

__global__ void scan_chunks_kernel(int* __restrict__ chunk_sums,
                                   int* __restrict__ offsets, int nch, int N,
                                   int E) {
  int t = threadIdx.x;  // one wave; nch <= 64
  int v = (t < nch) ? chunk_sums[t] : 0;
  int orig = v;
#pragma unroll
  for (int off = 1; off < 64; off <<= 1) {
    int y = __shfl_up(v, off);
    if (t >= off) v += y;
  }
  if (t < nch) chunk_sums[t] = v - orig;
  if (t == 0) offsets[N] = E;
}

__global__ void scan_block_kernel(const int* __restrict__ counts,
                                  const int* __restrict__ chunk_off,
                                  int* __restrict__ offsets,
                                  int* __restrict__ cursor, int N) {
  __shared__ int part[256];
  int b = blockIdx.x, t = threadIdx.x;
  int base = b * 1024 + t * 4;
  int v[4];
#pragma unroll
  for (int j = 0; j < 4; ++j) v[j] = (base + j < N) ? counts[base + j] : 0;
  int local = v[0] + v[1] + v[2] + v[3];
  part[t] = local;
  __syncthreads();
  for (int off = 1; off < 256; off <<= 1) {
    int x = 0;
    if (t >= off) x = part[t - off];
    __syncthreads();
    if (t >= off) part[t] += x;
    __syncthreads();
  }
  int run = chunk_off[b] + (part[t] - local);
#pragma unroll
  for (int j = 0; j < 4; ++j) {
    if (base + j < N) {
      offsets[base + j] = run;
      cursor[base + j] = run;
      run += v[j];
    }
  }
}

// ---------------------------------------------------------------------------
// Fused edge geometry + CSR scatter. rbf packed fp16 (10 x half2, stride 12
// uints for 16B alignment), dir fp32.
// ---------------------------------------------------------------------------
__global__ void edge_geom_kernel(const float* __restrict__ pos,
                                 const int* __restrict__ src,
                                 const int* __restrict__ tgt,
                                 int* __restrict__ cursor,
                                 float4* __restrict__ dir4_s,
                                 uint_t* __restrict__ rbh_s,
                                 int* __restrict__ src_s, int E) {
  int e = blockIdx.x * 256 + threadIdx.x;
  if (e >= E) return;
  const int sn = src[e];
  const int tn = tgt[e];
  const float rx = pos[tn * 3 + 0] - pos[sn * 3 + 0];
  const float ry = pos[tn * 3 + 1] - pos[sn * 3 + 1];
  const float rz = pos[tn * 3 + 2] - pos[sn * 3 + 2];
  const float dist = sqrtf(rx * rx + ry * ry + rz * rz);
  const float inv = 1.0f / dist;

  const float ang = dist * (PI_F / CUT_OFF_F);
  float s1, c1;
  sincosf(ang, &s1, &c1);
  float sk = s1, ck = c1;
  float rb[NUM_RBF];
  rb[0] = s1 * inv;
#pragma unroll
  for (int r = 1; r < NUM_RBF; ++r) {
    float sn2 = sk * c1 + ck * s1;
    ck = ck * c1 - sk * s1;
    sk = sn2;
    rb[r] = sk * inv;
  }

  const int p = atomicAdd(&cursor[tn], 1);
  dir4_s[p] = make_float4(rx * inv, ry * inv, rz * inv, dist);
  src_s[p] = sn;
  uint_t us[10];
#pragma unroll
  for (int q = 0; q < 10; ++q) us[q] = pack2h(rb[2 * q], rb[2 * q + 1]);
  uint_t* o = rbh_s + (size_t)p * 12;
  *reinterpret_cast<uint4*>(o) = make_uint4(us[0], us[1], us[2], us[3]);
  *reinterpret_cast<uint4*>(o + 4) = make_uint4(us[4], us[5], us[6], us[7]);
  *reinterpret_cast<uint2*>(o + 8) = make_uint2(us[8], us[9]);
}

// ---------------------------------------------------------------------------
// Node gather. fp16 natural-order gathers of s/vf, packed-fp16 rbf with
// v_dot2_f32_f16 filter dot (fp32 accumulate), shfl-broadcast src, x2 ILP.
// ---------------------------------------------------------------------------
#define NODES_PER_BLOCK 16

__device__ __forceinline__ float cutoff_f(float x) {
  return (x < CUT_OFF_F) ? 0.5f * (1.0f + __cosf(x * (PI_F / CUT_OFF_F))) : 0.f;
}

struct EdgeData {
  float4 dir;
  uint_t rbu[10];
  float sx, sy, sz, vx, vy, vz;
};

__device__ __forceinline__ void load_edge(int idx, int sn, int d,
                                          const ushort_t* __restrict__ s_half,
                                          const ushort_t* __restrict__ vf_half,
                                          const float4* __restrict__ dir4_s,
                                          const uint_t* __restrict__ rbh_s,
                                          EdgeData& ed) {
  ed.dir = dir4_s[idx];
  const uint_t* o = rbh_s + (size_t)idx * 12;
  uint4 u0 = *reinterpret_cast<const uint4*>(o);
  uint4 u1 = *reinterpret_cast<const uint4*>(o + 4);
  uint2 u2 = *reinterpret_cast<const uint2*>(o + 8);
  ed.rbu[0] = u0.x; ed.rbu[1] = u0.y; ed.rbu[2] = u0.z; ed.rbu[3] = u0.w;
  ed.rbu[4] = u1.x; ed.rbu[5] = u1.y; ed.rbu[6] = u1.z; ed.rbu[7] = u1.w;
  ed.rbu[8] = u2.x; ed.rbu[9] = u2.y;
  const ushort_t* sr = s_half + (size_t)sn * 384 + 3 * d;
  ed.sx = h2f(sr[0]); ed.sy = h2f(sr[1]); ed.sz = h2f(sr[2]);
  const ushort_t* vr = vf_half + (size_t)sn * 384 + 3 * d;
  ed.vx = h2f(vr[0]); ed.vy = h2f(vr[1]); ed.vz = h2f(vr[2]);
}

__global__ __launch_bounds__(128) void node_kernel(
    const ushort_t* __restrict__ s_half, const ushort_t* __restrict__ vf_half,
    const float4* __restrict__ dir4_s, const uint_t* __restrict__ rbh_s,
    const int* __restrict__ src_s, const int* __restrict__ offsets,
    const float* __restrict__ Wr, const float* __restrict__ br,
    float* __restrict__ out, int N, int E) {
  const int d = threadIdx.x;
  const int lane = d & 63;

  h2v wr0h[10], wr1h[10], wr2h[10];
#pragma unroll
  for (int q = 0; q < 10; ++q) {
    h2v w;
    w.x = (_Float16)Wr[(2 * q) * 384 + 3 * d + 0];
    w.y = (_Float16)Wr[(2 * q + 1) * 384 + 3 * d + 0];
    wr0h[q] = w;
    w.x = (_Float16)Wr[(2 * q) * 384 + 3 * d + 1];
    w.y = (_Float16)Wr[(2 * q + 1) * 384 + 3 * d + 1];
    wr1h[q] = w;
    w.x = (_Float16)Wr[(2 * q) * 384 + 3 * d + 2];
    w.y = (_Float16)Wr[(2 * q + 1) * 384 + 3 * d + 2];
    wr2h[q] = w;
  }
  const float br0 = br[3 * d + 0];
  const float br1 = br[3 * d + 1];
  const float br2 = br[3 * d + 2];

  for (int nn = 0; nn < NODES_PER_BLOCK; ++nn) {
    const int n = blockIdx.x * NODES_PER_BLOCK + nn;
    if (n >= N) break;

    const int start = offsets[n];
    const int end = offsets[n + 1];

    float accs = 0.f, av0 = 0.f, av1 = 0.f, av2 = 0.f;

    for (int base = start; base < end; base += 64) {
      const int m = min(64, end - base);
      int ld = base + lane;
      if (ld >= E) ld = E - 1;
      const int sn_l = src_s[ld];

      int i = 0;
      for (; i + 2 <= m; i += 2) {
        const int sn0 = __shfl(sn_l, i);
        const int sn1 = __shfl(sn_l, i + 1);
        EdgeData e0, e1;
        load_edge(base + i, sn0, d, s_half, vf_half, dir4_s, rbh_s, e0);
        load_edge(base + i + 1, sn1, d, s_half, vf_half, dir4_s, rbh_s, e1);

#pragma unroll
        for (int u = 0; u < 2; ++u) {
          const EdgeData& ed = (u == 0) ? e0 : e1;
          float f0 = br0, f1 = br1, f2 = br2;
#pragma unroll
          for (int q = 0; q < 10; ++q) {
            h2v r = u2h2(ed.rbu[q]);
            f0 = fdot2f(r, wr0h[q], f0);
            f1 = fdot2f(r, wr1h[q], f1);
            f2 = fdot2f(r, wr2h[q], f2);
          }
          f0 = cutoff_f(f0);
          f1 = cutoff_f(f1);
          f2 = cutoff_f(f2);
          const float m0 = ed.sx * f0;
          const float m1 = ed.sy * f1;
          const float m2 = ed.sz * f2;
          accs += m0;
          av0 += m2 * ed.dir.x + m1 * ed.vx;
          av1 += m2 * ed.dir.y + m1 * ed.vy;
          av2 += m2 * ed.dir.z + m1 * ed.vz;
        }
      }
      if (i < m) {
        const int sn0 = __shfl(sn_l, i);
        EdgeData e0;
        load_edge(base + i, sn0, d, s_half, vf_half, dir4_s, rbh_s, e0);
        float f0 = br0, f1 = br1, f2 = br2;
#pragma unroll
        for (int q = 0; q < 10; ++q) {
          h2v r = u2h2(e0.rbu[q]);
          f0 = fdot2f(r, wr0h[q], f0);
          f1 = fdot2f(r, wr1h[q], f1);
          f2 = fdot2f(r, wr2h[q], f2);
        }
        f0 = cutoff_f(f0);
        f1 = cutoff_f(f1);
        f2 = cutoff_f(f2);
        const float m0 = e0.sx * f0;
        const float m1 = e0.sy * f1;
        const float m2 = e0.sz * f2;
        accs += m0;
        av0 += m2 * e0.dir.x + m1 * e0.vx;
        av1 += m2 * e0.dir.y + m1 * e0.vy;
        av2 += m2 * e0.dir.z + m1 * e0.vz;
      }
    }

    out[(size_t)n * 384 + 3 * d + 0] = av0;
    out[(size_t)n * 384 + 3 * d + 1] = av1;
    out[(size_t)n * 384 + 3 * d + 2] = av2;
    out[(size_t)N * 384 + (size_t)n * 128 + d] = accs;
  }
}

// ---------------------------------------------------------------------------
extern "C" void kernel_launch(void* const* d_in, const int* in_sizes, int n_in,
                              void* d_out, int out_size, void* d_ws,
                              size_t ws_size, hipStream_t stream) {
  const float* vf  = (const float*)d_in[0];   // [N,128,3]
  const float* X   = (const float*)d_in[1];   // [N,128]
  const float* pos = (const float*)d_in[2];   // [N,3]
  const int* ei    = (const int*)d_in[3];     // [2,E]
  const float* W1  = (const float*)d_in[4];
  const float* b1  = (const float*)d_in[5];
  const float* W2  = (const float*)d_in[6];
  const float* b2  = (const float*)d_in[7];
  const float* Wr  = (const float*)d_in[8];
  const float* br  = (const float*)d_in[9];

  const int N = in_sizes[1] / D_DIM;
  const int E = in_sizes[3] / 2;
  const int* srcI = ei;
  const int* tgtI = ei + E;
  float* out = (float*)d_out;

  // workspace layout (16B-aligned chunks first)
  char* w = (char*)d_ws;
  float4* dir4_s    = (float4*)w;   w += (size_t)E * sizeof(float4);
  uint_t* rbh_s     = (uint_t*)w;   w += (size_t)E * 12 * sizeof(uint_t);
  ushort_t* s_half  = (ushort_t*)w; w += (size_t)N * 384 * sizeof(ushort_t);
  ushort_t* vf_half = (ushort_t*)w; w += (size_t)N * 384 * sizeof(ushort_t);
  int* src_s        = (int*)w;      w += (size_t)E * sizeof(int);
  int* counts       = (int*)w;      w += (size_t)N * sizeof(int);
  int* offsets      = (int*)w;      w += (size_t)(N + 1) * sizeof(int);
  int* cursor       = (int*)w;      w += (size_t)N * sizeof(int);
  int* chunks       = (int*)w;      w += 64 * sizeof(int);

  const int nch = (N + 1023) / 1024;  // 49 for N=50000

  zero_kernel<<<(N + 255) / 256, 256, 0, stream>>>(counts, N);
  proj_kernel<<<(N + 31) / 32, 256, 0, stream>>>(X, W1, b1, W2, b2, s_half, N);
  vf_cast_kernel<<<(N * 384 / 8 + 255) / 256, 256, 0, stream>>>(vf, vf_half,
                                                                N * 384 / 8);
  hist_kernel<<<(E + 255) / 256, 256, 0, stream>>>(tgtI, counts, E);
  chunk_sum_kernel<<<nch, 256, 0, stream>>>(counts, chunks, N);
  scan_chunks_kernel<<<1, 64, 0, stream>>>(chunks, offsets, nch, N, E);
  scan_block_kernel<<<nch, 256, 0, stream>>>(counts, chunks, offsets, cursor, N);
  edge_geom_kernel<<<(E + 255) / 256, 256, 0, stream>>>(pos, srcI, tgtI, cursor,
                                                        dir4_s, rbh_s, src_s, E);
  node_kernel<<<(N + NODES_PER_BLOCK - 1) / NODES_PER_BLOCK, 128, 0, stream>>>(
      s_half, vf_half, dir4_s, rbh_s, src_s, offsets, Wr, br, out, N, E);
}